// Round 1
// baseline (240.659 us; speedup 1.0000x reference)
//
#include <hip/hip_runtime.h>

// Problem constants: x [L,B,E], H heads, head dim 64.
#define L_DIM 1024
#define B_DIM 8
#define E_DIM 1024
#define H_DIM 16
#define HD 64
#define BH_DIM (B_DIM * H_DIM)  // 128

typedef float f32x4 __attribute__((ext_vector_type(4)));
typedef _Float16 f16_t;
typedef f16_t f16x4 __attribute__((ext_vector_type(4)));
typedef f16_t f16x8 __attribute__((ext_vector_type(8)));

// async global->LDS, 16 B per lane (m97 pattern): wave-uniform base + lane*16.
static __device__ __forceinline__ void gld16(const void* g, void* l) {
  __builtin_amdgcn_global_load_lds(
      (const __attribute__((address_space(1))) unsigned int*)g,
      (__attribute__((address_space(3))) unsigned int*)l, 16, 0, 0);
}

// fp32 -> f16 pre-convert of x, w_in, w_out (grid-stride over float4 units).
__global__ __launch_bounds__(256) void convert_f16(
    const float* __restrict__ x, const float* __restrict__ wi,
    const float* __restrict__ wo, f16_t* __restrict__ x16,
    f16_t* __restrict__ wi16, f16_t* __restrict__ wo16) {
  const int NX = (L_DIM * B_DIM * E_DIM) / 4;   // 2097152
  const int NWI = (3 * E_DIM * E_DIM) / 4;      // 786432
  const int NWO = (E_DIM * E_DIM) / 4;          // 262144
  const int total = NX + NWI + NWO;
  for (int i = blockIdx.x * blockDim.x + threadIdx.x; i < total;
       i += gridDim.x * blockDim.x) {
    const float4* src; f16_t* dst; int j;
    if (i < NX)            { src = (const float4*)x;  dst = x16;  j = i; }
    else if (i < NX + NWI) { src = (const float4*)wi; dst = wi16; j = i - NX; }
    else                   { src = (const float4*)wo; dst = wo16; j = i - NX - NWI; }
    const float4 v = src[j];
    f16x4 h = {(f16_t)v.x, (f16_t)v.y, (f16_t)v.z, (f16_t)v.w};
    *(f16x4*)(dst + (size_t)j * 4) = h;
  }
}

// ---------------------------------------------------------------------------
// QKV GEMM, 256x256 8-phase schedule (T2+T3+T4+T5 from the 8-phase template).
// C[8192,3072] = A[8192,1024] * B[3072,1024]^T + bias, scattered to q/k/v f16.
// 512 threads = 8 waves (2M x 4N), per-wave 128x64 output, BK=64, double-
// buffered 128 KiB LDS.  Raw s_barrier (no vmcnt drain!), counted vmcnt(4)
// once per K-tile, setprio around the 16-MFMA cluster, both-sides XOR swizzle
// (granule ^= row&7): gld16 writes linearly, so the swizzle is applied to the
// per-lane GLOBAL source address and to the ds_read address (guide rule 21).
//
// Stage schedule per iteration (tiles t0=2i in dbuf0, t1=2i+1 in dbuf1):
//   t0-phases: p0 A(t1)h0, p1 A(t1)h1, p2 B(t0+2)h0, p3 B(t0+2)h1, vmcnt(4)
//   t1-phases: p0 A(t0+2)h0, p1 A(t0+2)h1, p2 B(t1+2)h0, p3 B(t1+2)h1, vmcnt(4)
// At each vmcnt(4) the 4 newest loads (2 half-tiles) stay in flight; everything
// needed by the next tile's phase-0 ds_reads is >=4 phases old and drained.
// B slots free after each tile's phase 0 (all B-frags read there); A slots
// free after phase 3 -- staging never lands on live data (>=2 barriers apart).
// ---------------------------------------------------------------------------

#define GQ_FENCE asm volatile("" ::: "memory")
#define GQ_BARRIER do { GQ_FENCE; __builtin_amdgcn_s_barrier(); GQ_FENCE; } while (0)
// rule #18: sched_barrier(0) right after an inline-asm lgkmcnt wait.
#define GQ_LGKM0 do { asm volatile("s_waitcnt lgkmcnt(0)" ::: "memory"); \
                      __builtin_amdgcn_sched_barrier(0); } while (0)
#define GQ_VMCNT4 asm volatile("s_waitcnt vmcnt(4)" ::: "memory")

// stage one 128x64 half-tile (16 KB) = 2 x gld16 per thread (512 threads).
#define STAGE_A(d, ht, kt) do {                                              \
    gld16(Asrc + (size_t)(ht) * (128 * 1024) + (kt) * 64,                    \
          &As[(d) * 16384 + (ht) * 8192 + tid * 8]);                         \
    gld16(Asrc + (size_t)(ht) * (128 * 1024) + 64 * 1024 + (kt) * 64,        \
          &As[(d) * 16384 + (ht) * 8192 + 4096 + tid * 8]);                  \
  } while (0)
#define STAGE_B(d, ht, kt) do {                                              \
    gld16(Bsrc + (size_t)(ht) * (128 * 1024) + (kt) * 64,                    \
          &Bs[(d) * 16384 + (ht) * 8192 + tid * 8]);                         \
    gld16(Bsrc + (size_t)(ht) * (128 * 1024) + 64 * 1024 + (kt) * 64,        \
          &Bs[(d) * 16384 + (ht) * 8192 + 4096 + tid * 8]);                  \
  } while (0)

// swizzled frag pointer: logical byte = r*128 + ks*64 + quad*16, physical
// XORs (r&7)<<4.  r always = base + l16 so r&7 == l16&7.
static __device__ __forceinline__ const f16x8* fp16frag(
    const f16_t* tile, int r, int ks, int quad, int l16) {
  const int bo = (r * 128 + ks * 64 + quad * 16) ^ ((l16 & 7) << 4);
  return (const f16x8*)((const char*)tile + bo);
}

// one phase: 4 A ds_read_b128 (+8 B reads at g==0), 1 half-tile stage,
// barrier, lgkm0, 16 MFMA under setprio, [vmcnt(4)], barrier.
#define GQ_PHASE(d, g, STAGE_STMT, ENDWAIT) do {                             \
    f16x8 af_[2][2];                                                         \
    _Pragma("unroll") for (int f_ = 0; f_ < 2; ++f_)                         \
      _Pragma("unroll") for (int ks_ = 0; ks_ < 2; ++ks_)                    \
        af_[f_][ks_] = *fp16frag(&As[(d) * 16384],                           \
            wr * 128 + ((g) * 2 + f_) * 16 + l16, ks_, quad, l16);           \
    if ((g) == 0) {                                                          \
      _Pragma("unroll") for (int c_ = 0; c_ < 4; ++c_)                       \
        _Pragma("unroll") for (int ks_ = 0; ks_ < 2; ++ks_)                  \
          bf[c_][ks_] = *fp16frag(&Bs[(d) * 16384],                          \
              wc * 64 + c_ * 16 + l16, ks_, quad, l16);                      \
    }                                                                        \
    STAGE_STMT;                                                              \
    GQ_BARRIER;                                                              \
    GQ_LGKM0;                                                                \
    __builtin_amdgcn_s_setprio(1);                                           \
    _Pragma("unroll") for (int f_ = 0; f_ < 2; ++f_)                         \
      _Pragma("unroll") for (int c_ = 0; c_ < 4; ++c_)                       \
        _Pragma("unroll") for (int ks_ = 0; ks_ < 2; ++ks_)                  \
          acc[(g) * 2 + f_][c_] = __builtin_amdgcn_mfma_f32_16x16x32_f16(    \
              af_[f_][ks_], bf[c_][ks_], acc[(g) * 2 + f_][c_], 0, 0, 0);    \
    __builtin_amdgcn_s_setprio(0);                                           \
    ENDWAIT;                                                                 \
    GQ_BARRIER;                                                              \
  } while (0)

__global__ __launch_bounds__(512, 2) void gemm_qkv(
    const f16_t* __restrict__ A, const f16_t* __restrict__ B,
    const float* __restrict__ bias, f16_t* __restrict__ Oq,
    f16_t* __restrict__ Ok, f16_t* __restrict__ Ov) {
  constexpr int K = 1024;
  constexpr int NT = K / 64;  // 16 K-tiles
  __shared__ __align__(16) f16_t As[2 * 16384];  // 64 KB: dbuf x 256x64
  __shared__ __align__(16) f16_t Bs[2 * 16384];  // 64 KB

  const int tid = threadIdx.x;
  const int lane = tid & 63;
  const int w = tid >> 6;       // 0..7
  const int wr = w >> 2;        // M half
  const int wc = w & 3;         // N quarter
  const int quad = lane >> 4;
  const int l16 = lane & 15;

  // XCD-aware bijective swizzle: 384 wg = 8 XCDs x 48.
  const int bid = blockIdx.x;
  const int wg = (bid & 7) * 48 + (bid >> 3);
  const int tn = wg >> 5;       // 0..11
  const int tm = wg & 31;       // 0..31
  const int m0 = tm * 256;
  const int n0 = tn * 256;

  // staging: thread covers row srow (of a 128-row half), swizzled col block.
  const int srow = tid >> 3;
  const int scol = ((tid & 7) ^ (srow & 7)) * 8;  // pre-swizzled global col
  const f16_t* Asrc = A + (size_t)(m0 + srow) * K + scol;
  const f16_t* Bsrc = B + (size_t)(n0 + srow) * K + scol;

  f32x4 acc[8][4] = {};
  f16x8 bf[4][2];

  // Prologue: A(0), B(0), B(1); wait oldest 8 (A0+B0), leave B(1) in flight.
  STAGE_A(0, 0, 0); STAGE_A(0, 1, 0);
  STAGE_B(0, 0, 0); STAGE_B(0, 1, 0);
  STAGE_B(1, 0, 1); STAGE_B(1, 1, 1);
  GQ_VMCNT4;
  GQ_BARRIER;

  for (int it = 0; it < 8; ++it) {
    const int t1 = 2 * it + 1;
    const int ta = (2 * it + 2 < NT) ? 2 * it + 2 : NT - 1;  // clamped: keeps
    const int tb = (2 * it + 3 < NT) ? 2 * it + 3 : NT - 1;  // vmcnt counts fixed
    // tile t0 = 2*it from dbuf0
    GQ_PHASE(0, 0, STAGE_A(1, 0, t1), );
    GQ_PHASE(0, 1, STAGE_A(1, 1, t1), );
    GQ_PHASE(0, 2, STAGE_B(0, 0, ta), );
    GQ_PHASE(0, 3, STAGE_B(0, 1, ta), GQ_VMCNT4);
    // tile t1 from dbuf1
    GQ_PHASE(1, 0, STAGE_A(0, 0, ta), );
    GQ_PHASE(1, 1, STAGE_A(0, 1, ta), );
    GQ_PHASE(1, 2, STAGE_B(1, 0, tb), );
    GQ_PHASE(1, 3, STAGE_B(1, 1, tb), GQ_VMCNT4);
  }

  // Epilogue: C/D layout col=l16, row=quad*4+r.  q/k/v scatter as before.
#pragma unroll
  for (int i = 0; i < 8; ++i) {
    const int mbase = m0 + wr * 128 + i * 16 + quad * 4;
#pragma unroll
    for (int c = 0; c < 4; ++c) {
      const int n = n0 + wc * 64 + c * 16 + l16;
      const float bv = bias[n];
      const int chunk = n >> 10;      // 0=q 1=k 2=v (uniform per 16-wide frag)
      const int e = n & 1023;
      const int h = e >> 6;
      const int d = e & 63;
#pragma unroll
      for (int r = 0; r < 4; ++r) {
        const int m = mbase + r;
        const int l = m >> 3, b = m & 7;          // row m = l*B + b
        const size_t idx = ((size_t)(b * H_DIM + h) * L_DIM + l) * HD + d;
        const float val = acc[i][c][r] + bv;
        if (chunk == 0)      Oq[idx] = (f16_t)(val * 0.125f);  // 64^-0.5
        else if (chunk == 1) Ok[idx] = (f16_t)val;
        else                 Ov[idx] = (f16_t)val;
      }
    }
  }
}

// ---------------------------------------------------------------------------
// Out-proj GEMM kept on the m97 128x128 structure (N=1024 -> only 128 blocks
// at 256^2, half the GPU idle; revisit later).
// ---------------------------------------------------------------------------
template <int MODE>
__global__ __launch_bounds__(256, 2) void gemm_f16(
    const f16_t* __restrict__ A, const f16_t* __restrict__ B,
    const float* __restrict__ bias, void* __restrict__ O0v,
    void* __restrict__ O1v, void* __restrict__ O2v) {
  constexpr int K = 1024;
  __shared__ __align__(16) f16_t As[128 * 32];
  __shared__ __align__(16) f16_t Bs[128 * 32];

  const int tid = threadIdx.x;
  const int lane = tid & 63;
  const int wave = tid >> 6;
  const int wm = (wave & 1) * 64;
  const int wn = (wave >> 1) * 64;
  const int quad = lane >> 4;
  const int l16 = lane & 15;
  const int m0 = blockIdx.y * 128;
  const int n0 = blockIdx.x * 128;

  const int cr = tid >> 2;
  const int cc = (tid & 3) * 8;

  f32x4 acc[4][4] = {};

  for (int k0 = 0; k0 < K; k0 += 32) {
    __syncthreads();
    gld16(A + (size_t)(m0 + cr) * K + k0 + cc,      As + tid * 8);
    gld16(A + (size_t)(m0 + 64 + cr) * K + k0 + cc, As + 2048 + tid * 8);
    gld16(B + (size_t)(n0 + cr) * K + k0 + cc,      Bs + tid * 8);
    gld16(B + (size_t)(n0 + 64 + cr) * K + k0 + cc, Bs + 2048 + tid * 8);
    __syncthreads();

    f16x8 af[4], bfr[4];
#pragma unroll
    for (int t = 0; t < 4; ++t) {
      af[t]  = *(const f16x8*)&As[(wm + t * 16 + l16) * 32 + quad * 8];
      bfr[t] = *(const f16x8*)&Bs[(wn + t * 16 + l16) * 32 + quad * 8];
    }
#pragma unroll
    for (int i = 0; i < 4; ++i)
#pragma unroll
      for (int j = 0; j < 4; ++j)
        acc[i][j] = __builtin_amdgcn_mfma_f32_16x16x32_f16(af[i], bfr[j], acc[i][j], 0, 0, 0);
  }

#pragma unroll
  for (int i = 0; i < 4; ++i) {
    const int mbase = m0 + wm + i * 16 + quad * 4;
#pragma unroll
    for (int j = 0; j < 4; ++j) {
      const int n = n0 + wn + j * 16 + l16;
      const float bv = bias[n];
      if (MODE == 0) {
        f16_t* O0 = (f16_t*)O0v; f16_t* O1 = (f16_t*)O1v; f16_t* O2 = (f16_t*)O2v;
        const int chunk = n >> 10;
        const int e = n & 1023;
        const int h = e >> 6;
        const int d = e & 63;
#pragma unroll
        for (int r = 0; r < 4; ++r) {
          const int m = mbase + r;
          const int l = m >> 3, b = m & 7;
          const size_t idx = ((size_t)(b * H_DIM + h) * L_DIM + l) * HD + d;
          const float val = acc[i][j][r] + bv;
          if (chunk == 0)      O0[idx] = (f16_t)(val * 0.125f);
          else if (chunk == 1) O1[idx] = (f16_t)val;
          else                 O2[idx] = (f16_t)val;
        }
      } else {
        float* O0 = (float*)O0v;
#pragma unroll
        for (int r = 0; r < 4; ++r) {
          const int m = mbase + r;
          O0[(size_t)m * E_DIM + n] = acc[i][j][r] + bv;
        }
      }
    }
  }
}

// Attention v5 (unchanged this round): all-f16, 64 q per wave, S^T = K.Q^T
// with permuted key->row mapping, in-register P, V^T staged in-kernel.
__global__ __launch_bounds__(256, 2) void attn_f16(
    const f16_t* __restrict__ Q, const f16_t* __restrict__ K,
    const f16_t* __restrict__ V, f16_t* __restrict__ O) {
  constexpr int KSTR = 70;
  __shared__ __align__(16) f16_t Ks[64 * KSTR];
  __shared__ __align__(16) f16_t Vs[64 * KSTR];
  __shared__ float Ls[4][64];

  const int tid = threadIdx.x;
  const int lane = tid & 63;
  const int w = tid >> 6;
  const int quad = lane >> 4;
  const int l16 = lane & 15;
  const int bh = blockIdx.y;
  const int q0 = blockIdx.x * 256 + w * 64;

  const f16_t* Qb = Q + (size_t)bh * L_DIM * HD;
  const f16_t* Kb = K + (size_t)bh * L_DIM * HD;
  const f16_t* Vb = V + (size_t)bh * L_DIM * HD;

  f16x8 qf[4][2];
#pragma unroll
  for (int nt = 0; nt < 4; ++nt)
#pragma unroll
    for (int kc = 0; kc < 2; ++kc)
      qf[nt][kc] = *(const f16x8*)(Qb + (size_t)(q0 + nt * 16 + l16) * HD + kc * 32 + quad * 8);

  f32x4 oacc[4][4] = {};
  float rsum[4] = {0.0f, 0.0f, 0.0f, 0.0f};

  const int sr = tid >> 3;
  const int sc8 = (tid & 7) * 8;
  const int va = tid & 31;
  const int vg = tid >> 5;
  const int rA = (l16 >> 2) * 8 + (l16 & 3);

  for (int kt = 0; kt < 16; ++kt) {
    __syncthreads();
    {
      const f16_t* kp = Kb + (size_t)(kt * 64) * HD;
#pragma unroll
      for (int rr = 0; rr < 2; ++rr) {
        const int row = sr + rr * 32;
        *(f16x8*)&Ks[row * KSTR + sc8] = *(const f16x8*)(kp + (size_t)row * HD + sc8);
      }
      const f16_t* vp = Vb + (size_t)(kt * 64 + vg * 8) * HD + 2 * va;
      unsigned int vd[8];
#pragma unroll
      for (int i = 0; i < 8; ++i) vd[i] = *(const unsigned int*)(vp + (size_t)i * HD);
      union { unsigned int u[4]; f16x8 v; } lo, hi;
#pragma unroll
      for (int i = 0; i < 4; ++i) {
        lo.u[i] = (vd[2 * i] & 0xffffu) | (vd[2 * i + 1] << 16);
        hi.u[i] = (vd[2 * i] >> 16) | (vd[2 * i + 1] & 0xffff0000u);
      }
      *(f16x8*)&Vs[(2 * va) * KSTR + vg * 8] = lo.v;
      *(f16x8*)&Vs[(2 * va + 1) * KSTR + vg * 8] = hi.v;
    }
    __syncthreads();

#pragma unroll
    for (int c = 0; c < 2; ++c) {
      f32x4 sc[2][4] = {};
#pragma unroll
      for (int h = 0; h < 2; ++h) {
        const int row = c * 32 + h * 4 + rA;
#pragma unroll
        for (int kc = 0; kc < 2; ++kc) {
          const f16x8 ka = *(const f16x8*)&Ks[row * KSTR + kc * 32 + quad * 8];
#pragma unroll
          for (int nt = 0; nt < 4; ++nt)
            sc[h][nt] = __builtin_amdgcn_mfma_f32_16x16x32_f16(ka, qf[nt][kc], sc[h][nt], 0, 0, 0);
        }
      }

      f16x8 pa[4];
#pragma unroll
      for (int nt = 0; nt < 4; ++nt)
#pragma unroll
        for (int h = 0; h < 2; ++h)
#pragma unroll
          for (int r = 0; r < 4; ++r) {
            const float e = __expf(sc[h][nt][r]);
            rsum[nt] += e;
            pa[nt][h * 4 + r] = (f16_t)e;
          }

#pragma unroll
      for (int nd = 0; nd < 4; ++nd) {
        const f16x8 vb = *(const f16x8*)&Vs[(nd * 16 + l16) * KSTR + c * 32 + quad * 8];
#pragma unroll
        for (int nt = 0; nt < 4; ++nt)
          oacc[nt][nd] = __builtin_amdgcn_mfma_f32_16x16x32_f16(pa[nt], vb, oacc[nt][nd], 0, 0, 0);
      }
    }
  }

#pragma unroll
  for (int nt = 0; nt < 4; ++nt) {
    float rs = rsum[nt];
    rs += __shfl_xor(rs, 16); rs += __shfl_xor(rs, 32);
    if (quad == 0) Ls[w][nt * 16 + l16] = rs;
  }
  asm volatile("s_waitcnt lgkmcnt(0)" ::: "memory");

  const int b = bh >> 4;
  const int h = bh & 15;
#pragma unroll
  for (int nt = 0; nt < 4; ++nt)
#pragma unroll
    for (int r = 0; r < 4; ++r) {
      const int ql = nt * 16 + quad * 4 + r;
      const float inv = 1.0f / Ls[w][ql];
      const int qrow = q0 + ql;
#pragma unroll
      for (int nd = 0; nd < 4; ++nd) {
        const int d = nd * 16 + l16;
        O[((size_t)qrow * B_DIM + b) * E_DIM + h * HD + d] = (f16_t)(oacc[nt][nd][r] * inv);
      }
    }
}

extern "C" void kernel_launch(void* const* d_in, const int* in_sizes, int n_in,
                              void* d_out, int out_size, void* d_ws, size_t ws_size,
                              hipStream_t stream) {
  const float* x     = (const float*)d_in[0];
  const float* w_in  = (const float*)d_in[1];
  const float* b_in  = (const float*)d_in[2];
  const float* w_out = (const float*)d_in[3];
  const float* b_out = (const float*)d_in[4];

  const size_t TS = (size_t)BH_DIM * L_DIM * HD;  // 8M elements per tensor
  f16_t* q16  = (f16_t*)d_ws;
  f16_t* k16  = q16 + TS;
  f16_t* v16  = k16 + TS;
  f16_t* x16  = v16 + TS;
  f16_t* wi16 = x16 + TS;
  f16_t* wo16 = wi16 + (size_t)3 * E_DIM * E_DIM;
  f16_t* ao16 = x16;   // alias: x16 dead after QKV GEMM

  // 0) fp32 -> f16 pre-convert (x, w_in, w_out)
  convert_f16<<<4096, 256, 0, stream>>>(x, w_in, w_out, x16, wi16, wo16);
  // 1) QKV projection: 256^2 8-phase kernel, 384 wg x 512 thr
  gemm_qkv<<<384, 512, 0, stream>>>(x16, wi16, b_in, q16, k16, v16);
  // 2) attention: 128 (b,h) x 4 q-blocks of 256
  attn_f16<<<dim3(4, 128), 256, 0, stream>>>(q16, k16, v16, ao16);
  // 3) out projection: [8192,1024] x [1024,1024]^T -> fp32 d_out
  gemm_f16<1><<<dim3(8, 64), 256, 0, stream>>>(ao16, wo16, b_out, d_out, nullptr, nullptr);
}